// Round 7
// baseline (199.050 us; speedup 1.0000x reference)
//
#include <hip/hip_runtime.h>
#include <cstdint>
#include <cstddef>

#define DEVI __device__ __forceinline__

typedef __bf16 bf16x8 __attribute__((ext_vector_type(8)));
typedef __bf16 bf16x2 __attribute__((ext_vector_type(2)));
typedef float floatx4 __attribute__((ext_vector_type(4)));
typedef unsigned short us4v __attribute__((ext_vector_type(4)));
typedef unsigned short us8 __attribute__((ext_vector_type(8)));

static_assert(sizeof(bf16x8) == 16, "bf16x8 must be 16B");

// ---------------- helpers ----------------

#if __has_builtin(__builtin_amdgcn_cvt_pk_bf16_f32)
DEVI unsigned short f2bf(float f) {
  union { bf16x2 v; unsigned short u[2]; } c;
  c.v = __builtin_amdgcn_cvt_pk_bf16_f32(f, 0.f);
  return c.u[0];
}
DEVI unsigned int pk2bf(float a, float b) {
  union { bf16x2 v; unsigned int u; } c;
  c.v = __builtin_amdgcn_cvt_pk_bf16_f32(a, b);
  return c.u;
}
#else
DEVI unsigned short f2bf(float f) {
  unsigned int u = __float_as_uint(f);
  u += 0x7fffu + ((u >> 16) & 1u);   // RNE
  return (unsigned short)(u >> 16);
}
DEVI unsigned int pk2bf(float a, float b) {
  return (unsigned int)f2bf(a) | ((unsigned int)f2bf(b) << 16);
}
#endif

DEVI float exp2c(float x) {
#if __has_builtin(__builtin_amdgcn_exp2f)
  return __builtin_amdgcn_exp2f(x);
#else
  return exp2f(x);
#endif
}

DEVI bf16x8 ld8(const unsigned short* p) { return *(const bf16x8*)p; }

typedef const __attribute__((address_space(1))) void* gas_ptr;
typedef __attribute__((address_space(3))) void* las_ptr;

DEVI void gld16(const void* g, void* l) {
  __builtin_amdgcn_global_load_lds((gas_ptr)g, (las_ptr)l, 16, 0, 0);
}

#define WAIT_LGKM0() __builtin_amdgcn_s_waitcnt(0xc07f)   // lgkmcnt(0) only

// ---------------- fused prep: mask bitpack + nodes cvt + weight transposes ----------------
// pm layout (wave-transposed): pm[((b*2048+q)*4 + w)*16 + it] covers keys
// (it*4+w)*32 .. +31 of row q.
__global__ __launch_bounds__(256) void prep_k(
    const float* __restrict__ nodes, const void* __restrict__ mask,
    const float* __restrict__ wq, const float* __restrict__ wkv,
    const float* __restrict__ wo,
    unsigned short* __restrict__ XB, unsigned short* __restrict__ WQKVT,
    unsigned short* __restrict__ WOT, unsigned int* __restrict__ pm) {
  int bid = blockIdx.x;
  if (bid < 8192) {
    __shared__ int mode;
    const unsigned int* md = (const unsigned int*)mask;
    unsigned int probe = md[threadIdx.x];
    bool odd = (probe > 1u && probe != 0x3f800000u);
    if (threadIdx.x == 0) mode = 0;
    __syncthreads();
    if (odd) atomicOr(&mode, 1);
    __syncthreads();
    int byteMode = mode;
    int t = bid * 256 + threadIdx.x;
    int lane = threadIdx.x & 63;
    unsigned int n;
    if (byteMode) {
      unsigned int x = md[t];
      n = ((x & 0xffu) ? 1u : 0u) | ((x & 0xff00u) ? 2u : 0u) |
          ((x & 0xff0000u) ? 4u : 0u) | ((x >> 24) ? 8u : 0u);
    } else {
      uint4 v = ((const uint4*)mask)[t];
      n = (v.x ? 1u : 0u) | (v.y ? 2u : 0u) | (v.z ? 4u : 0u) | (v.w ? 8u : 0u);
    }
    unsigned int w = n << ((lane & 7) * 4);
    w |= __shfl_xor(w, 1);
    w |= __shfl_xor(w, 2);
    w |= __shfl_xor(w, 4);
    if ((lane & 7) == 0) {
      unsigned int lin = (unsigned int)(t >> 3);   // global word index
      unsigned int q_lin = lin >> 6;               // b*2048+q
      unsigned int word = lin & 63;                // it*4 + wave
      pm[(q_lin * 4 + (word & 3)) * 16 + (word >> 2)] = w;
    }
  } else if (bid < 10240) {
    int i = (bid - 8192) * 256 + threadIdx.x;
    float4 v = ((const float4*)nodes)[i];
    us4v o;
    o[0] = f2bf(v.x); o[1] = f2bf(v.y); o[2] = f2bf(v.z); o[3] = f2bf(v.w);
    *(us4v*)(XB + (size_t)i * 4) = o;
  } else {
    int tb = bid - 10240;
    int x = tb & 15, y = (tb >> 4) & 7, z = tb >> 7;
    const float* src; unsigned short* dst; int C, c0;
    if (z == 0)      { if (x >= 8) return; src = wq;  dst = WQKVT; C = 512;  c0 = 0; }
    else if (z == 1) { src = wkv; dst = WQKVT; C = 1024; c0 = 512; }
    else             { if (x >= 8) return; src = wo;  dst = WOT;  C = 512;  c0 = 0; }
    __shared__ unsigned short t2[64 * 64];
    const int t = threadIdx.x;
    const int ct = x * 64, rt = y * 64;
    for (int p = 0; p < 4; p++) {
      int kl = p * 16 + (t >> 4);
      int cc = (t & 15) * 4;
      float4 v = *(const float4*)&src[(size_t)(rt + kl) * C + ct + cc];
      float f[4] = {v.x, v.y, v.z, v.w};
      for (int i = 0; i < 4; i++) {
        int c = cc + i;
        t2[c * 64 + (kl ^ (c & 56))] = f2bf(f[i]);
      }
    }
    __syncthreads();
    for (int p = 0; p < 2; p++) {
      int c = p * 32 + (t >> 3);
      int kc = (t & 7) * 8;
      us8 v = *(const us8*)&t2[c * 64 + (kc ^ (c & 56))];
      *(us8*)&dst[(size_t)(c0 + ct + c) * 512 + rt + kc] = v;
    }
  }
}

// ---------------- QKV GEMM: 64x128 tiles, double-buffered, grid (64,12) ----------------
__global__ __launch_bounds__(256) void gemm_qkv_k(
    const unsigned short* __restrict__ A,    // [4096][512]
    const unsigned short* __restrict__ Bt,   // [1536][512]
    const float* __restrict__ bq, const float* __restrict__ bkv,
    unsigned short* __restrict__ Qo, unsigned short* __restrict__ Ko,
    unsigned short* __restrict__ VTo) {
  __shared__ unsigned short smem[12288];     // 24 KB: 2 bufs x (sA 2048 + sB 4096)
  const int tid = threadIdx.x;
  const int wave = tid >> 6, lane = tid & 63, quad = lane >> 4, l16 = lane & 15;
  const int wm = wave >> 1, wn = wave & 1;
  const int bm = blockIdx.x, bn = blockIdx.y;
  floatx4 acc[2][4] = {};
  const int arow = lane >> 2;
  const int ag = lane & 3;

  auto stage = [&](int kt, int buf) {
    unsigned short* sA = smem + buf * 6144;
    unsigned short* sB = sA + 2048;
    int rowA = wave * 16 + arow;
    int gA = ag ^ (rowA & 3);
    gld16(&A[(size_t)(bm * 64 + rowA) * 512 + kt * 32 + gA * 8], &sA[(wave * 16) * 32]);
    for (int p = 0; p < 2; p++) {
      int rowB = p * 64 + wave * 16 + arow;
      int gB = ag ^ (rowB & 3);
      gld16(&Bt[(size_t)(bn * 128 + rowB) * 512 + kt * 32 + gB * 8],
            &sB[(p * 64 + wave * 16) * 32]);
    }
  };

  stage(0, 0);
  for (int kt = 0; kt < 16; kt++) {
    __syncthreads();                          // drains vmcnt: buf[kt&1] ready
    if (kt + 1 < 16) stage(kt + 1, (kt + 1) & 1);
    const unsigned short* sA = smem + (kt & 1) * 6144;
    const unsigned short* sB = sA + 2048;
    bf16x8 aF[2], bF[4];
    int swz = (quad ^ (l16 & 3)) * 8;
    for (int i = 0; i < 2; i++) aF[i] = ld8(&sA[(wm * 32 + i * 16 + l16) * 32 + swz]);
    for (int j = 0; j < 4; j++) bF[j] = ld8(&sB[(wn * 64 + j * 16 + l16) * 32 + swz]);
    for (int i = 0; i < 2; i++)
      for (int j = 0; j < 4; j++)
        acc[i][j] = __builtin_amdgcn_mfma_f32_16x16x32_bf16(aF[i], bF[j], acc[i][j], 0, 0, 0);
  }

  const int sec = bn * 2 + wn;               // 0..23: Q heads 0-7, K 8-15, V 16-23
  float bias[4];
  float scale = 1.0f;
  if (sec < 8) {
    for (int j = 0; j < 4; j++) bias[j] = bq[sec * 64 + j * 16 + l16];
    scale = 0.18033688011112042f;            // 0.125 * log2(e)
  } else {
    for (int j = 0; j < 4; j++) bias[j] = bkv[(sec - 8) * 64 + j * 16 + l16];
  }
  const int gr0 = bm * 64 + wm * 32;
  const int b = gr0 >> 11, n0 = gr0 & 2047;
  unsigned short* pw = smem + wave * 2048;
  __syncthreads();
  if (sec < 16) {
    for (int i = 0; i < 2; i++)
      for (int j = 0; j < 4; j++) {
        int cg = j * 2 + (l16 >> 3), ci = l16 & 7;
        for (int r = 0; r < 4; r++) {
          int row = i * 16 + quad * 4 + r;
          pw[row * 64 + ((cg ^ (row & 7)) * 8) + ci] = f2bf((acc[i][j][r] + bias[j]) * scale);
        }
      }
    WAIT_LGKM0();
    unsigned short* dst = (sec < 8) ? Qo + ((size_t)(b * 8 + sec) * 2048 + n0) * 64
                                    : Ko + ((size_t)(b * 8 + sec - 8) * 2048 + n0) * 64;
    for (int p = 0; p < 4; p++) {
      int row = p * 8 + (lane >> 3);
      int c8 = lane & 7;
      us8 v = *(const us8*)&pw[row * 64 + ((c8 ^ (row & 7)) * 8)];
      *(us8*)&dst[(size_t)row * 64 + c8 * 8] = v;
    }
  } else {
    // V: [64 d][32 n], keys s-permuted per 32-block: s = quad*8 + i*4 + r
    for (int i = 0; i < 2; i++)
      for (int j = 0; j < 4; j++) {
        int d = j * 16 + l16;
        us4v t;
        for (int r = 0; r < 4; r++) t[r] = f2bf(acc[i][j][r] + bias[j]);
        *(us4v*)&pw[d * 32 + ((quad ^ (d & 3)) * 8) + i * 4] = t;
      }
    WAIT_LGKM0();
    unsigned short* dst = VTo + (size_t)(b * 8 + sec - 16) * 64 * 2048 + n0;
    for (int p = 0; p < 4; p++) {
      int d = p * 16 + (lane >> 2);
      int c4 = lane & 3;
      us8 v = *(const us8*)&pw[d * 32 + ((c4 ^ (d & 3)) * 8)];
      *(us8*)&dst[(size_t)d * 2048 + c4 * 8] = v;
    }
  }
}

// ---------------- flash attention (barrier-free, zero-LDS main loop) ----------------
// 4 waves, 64 q shared; wave owns 32-key slice per iter (128 keys/block-iter,
// 16 iters). ALL operands loaded directly global->VGPR (L2-resident, 16B/lane
// coalesced). No staging, no barriers in loop; 17 KB LDS only for the final
// split-K O reduction.
__global__ __launch_bounds__(256, 3) void attn_k(
    const unsigned short* __restrict__ Q,    // [16][2048][64], pre-scaled
    const unsigned short* __restrict__ K,    // [16][2048][64]
    const unsigned short* __restrict__ Vt,   // [16][64][2048] s-permuted
    const unsigned int* __restrict__ pm,     // wave-transposed packed mask
    unsigned short* __restrict__ AO) {       // [2][2048][512]
  __shared__ float Ored[4096];               // 16 KB [64q][64d] swizzled
  __shared__ float lsumB[4][64];
  const int tid = threadIdx.x;
  const int wave = tid >> 6, lane = tid & 63, quad = lane >> 4, l16 = lane & 15;
  const int bh = blockIdx.x, qt = blockIdx.y, b = bh >> 3, h = bh & 7;
  const int q0 = qt * 64;
  const unsigned short* Qb = Q + (size_t)bh * 2048 * 64;
  const unsigned short* Kb = K + (size_t)bh * 2048 * 64;
  const unsigned short* Vb = Vt + (size_t)bh * 64 * 2048;

  bf16x8 qF[4][2];
  for (int qb = 0; qb < 4; qb++) {
    qF[qb][0] = ld8(&Qb[(size_t)(q0 + qb * 16 + l16) * 64 + quad * 8]);
    qF[qb][1] = ld8(&Qb[(size_t)(q0 + qb * 16 + l16) * 64 + 32 + quad * 8]);
  }

  size_t mbase[4];
  for (int qb = 0; qb < 4; qb++)
    mbase[qb] = ((size_t)(b * 2048 + q0 + qb * 16 + l16) * 4 + wave) * 16;

  floatx4 oacc[4][4] = {};                   // [db][qb]
  float lsum[4] = {0.f, 0.f, 0.f, 0.f};

  for (int it = 0; it < 16; ++it) {
    const int k0w = it * 128 + wave * 32;

    // V fragments (s-ordered rows; issued early, used last)
    bf16x8 va[4];
    for (int db = 0; db < 4; db++)
      va[db] = ld8(&Vb[(size_t)(db * 16 + l16) * 2048 + k0w + quad * 8]);

    unsigned int mw[4];
    for (int qb = 0; qb < 4; qb++) mw[qb] = pm[mbase[qb] + it];

    union uB { bf16x8 v; unsigned int d[4]; } pf[4];
    for (int k2 = 0; k2 < 2; k2++) {
      const unsigned short* kr = &Kb[(size_t)(k0w + k2 * 16 + l16) * 64 + quad * 8];
      bf16x8 kf0 = ld8(kr);
      bf16x8 kf1 = ld8(kr + 32);
      floatx4 st[4];
      for (int qb = 0; qb < 4; qb++) {
        floatx4 z = {0.f, 0.f, 0.f, 0.f};
        z = __builtin_amdgcn_mfma_f32_16x16x32_bf16(kf0, qF[qb][0], z, 0, 0, 0);
        st[qb] = __builtin_amdgcn_mfma_f32_16x16x32_bf16(kf1, qF[qb][1], z, 0, 0, 0);
      }
      for (int qb = 0; qb < 4; qb++) {
        unsigned int w = mw[qb];
        int base = k2 * 16 + quad * 4;
        float e0 = exp2c(st[qb][0]); e0 = ((w >> (base + 0)) & 1u) ? e0 : 0.f;
        float e1 = exp2c(st[qb][1]); e1 = ((w >> (base + 1)) & 1u) ? e1 : 0.f;
        float e2 = exp2c(st[qb][2]); e2 = ((w >> (base + 2)) & 1u) ? e2 : 0.f;
        float e3 = exp2c(st[qb][3]); e3 = ((w >> (base + 3)) & 1u) ? e3 : 0.f;
        lsum[qb] += (e0 + e1) + (e2 + e3);
        pf[qb].d[k2 * 2]     = pk2bf(e0, e1);
        pf[qb].d[k2 * 2 + 1] = pk2bf(e2, e3);
      }
    }

    for (int db = 0; db < 4; db++)
      for (int qb = 0; qb < 4; qb++)
        oacc[db][qb] =
            __builtin_amdgcn_mfma_f32_16x16x32_bf16(va[db], pf[qb].v, oacc[db][qb], 0, 0, 0);
  }

  // lsum: reduce across quads; lane(quad,l16) publishes q = quad*16+l16
  for (int qb = 0; qb < 4; qb++) {
    lsum[qb] += __shfl_xor(lsum[qb], 16);
    lsum[qb] += __shfl_xor(lsum[qb], 32);
  }
  lsumB[wave][quad * 16 + l16] = lsum[quad];

  // split-K reduction: 4 sequential read-add rounds into Ored (swizzled)
  for (int w = 0; w < 4; w++) {
    if (wave == w) {
      for (int db = 0; db < 4; db++)
        for (int qb = 0; qb < 4; qb++) {
          int q = qb * 16 + l16;
          int off = q * 64 + (((db * 4 + quad) ^ l16) & 15) * 4;
          if (w == 0) {
            *(floatx4*)&Ored[off] = oacc[db][qb];
          } else {
            floatx4 t = *(floatx4*)&Ored[off];
            t += oacc[db][qb];
            *(floatx4*)&Ored[off] = t;
          }
        }
    }
    __syncthreads();
  }

  {
    int q = tid >> 2, dblk = tid & 3;
    float inv = 1.0f / (lsumB[0][q] + lsumB[1][q] + lsumB[2][q] + lsumB[3][q]);
    float o[16];
    for (int i = 0; i < 4; i++) {
      int dg = dblk * 4 + i;
      int off = q * 64 + ((dg ^ q) & 15) * 4;
      floatx4 s = *(floatx4*)&Ored[off];
      for (int r = 0; r < 4; r++) o[i * 4 + r] = s[r] * inv;
    }
    us8 v0, v1;
    for (int i = 0; i < 8; i++) { v0[i] = f2bf(o[i]); v1[i] = f2bf(o[8 + i]); }
    unsigned short* dst = &AO[((size_t)b * 2048 + q0 + q) * 512 + h * 64 + dblk * 16];
    *(us8*)dst = v0;
    *(us8*)(dst + 8) = v1;
  }
}

// ---------------- out GEMM: 64x128 tiles, double-buffered, grid (64,4) ----------------
__global__ __launch_bounds__(256) void gemm_out_k(
    const unsigned short* __restrict__ A,    // [4096][512]
    const unsigned short* __restrict__ Bt,   // [512][512]
    const float* __restrict__ bo, float* __restrict__ out) {
  __shared__ unsigned short smem[12288];
  const int tid = threadIdx.x;
  const int wave = tid >> 6, lane = tid & 63, quad = lane >> 4, l16 = lane & 15;
  const int wm = wave >> 1, wn = wave & 1;
  const int bm = blockIdx.x, bn = blockIdx.y;
  floatx4 acc[2][4] = {};
  const int arow = lane >> 2;
  const int ag = lane & 3;

  auto stage = [&](int kt, int buf) {
    unsigned short* sA = smem + buf * 6144;
    unsigned short* sB = sA + 2048;
    int rowA = wave * 16 + arow;
    int gA = ag ^ (rowA & 3);
    gld16(&A[(size_t)(bm * 64 + rowA) * 512 + kt * 32 + gA * 8], &sA[(wave * 16) * 32]);
    for (int p = 0; p < 2; p++) {
      int rowB = p * 64 + wave * 16 + arow;
      int gB = ag ^ (rowB & 3);
      gld16(&Bt[(size_t)(bn * 128 + rowB) * 512 + kt * 32 + gB * 8],
            &sB[(p * 64 + wave * 16) * 32]);
    }
  };

  stage(0, 0);
  for (int kt = 0; kt < 16; kt++) {
    __syncthreads();
    if (kt + 1 < 16) stage(kt + 1, (kt + 1) & 1);
    const unsigned short* sA = smem + (kt & 1) * 6144;
    const unsigned short* sB = sA + 2048;
    bf16x8 aF[2], bF[4];
    int swz = (quad ^ (l16 & 3)) * 8;
    for (int i = 0; i < 2; i++) aF[i] = ld8(&sA[(wm * 32 + i * 16 + l16) * 32 + swz]);
    for (int j = 0; j < 4; j++) bF[j] = ld8(&sB[(wn * 64 + j * 16 + l16) * 32 + swz]);
    for (int i = 0; i < 2; i++)
      for (int j = 0; j < 4; j++)
        acc[i][j] = __builtin_amdgcn_mfma_f32_16x16x32_bf16(aF[i], bF[j], acc[i][j], 0, 0, 0);
  }
  for (int i = 0; i < 2; i++)
    for (int j = 0; j < 4; j++) {
      int gc = bn * 128 + wn * 64 + j * 16 + l16;
      float bb = bo[gc];
      for (int r = 0; r < 4; r++) {
        int gr = bm * 64 + wm * 32 + i * 16 + quad * 4 + r;
        out[(size_t)gr * 512 + gc] = acc[i][j][r] + bb;
      }
    }
}

// ---------------- launch ----------------
extern "C" void kernel_launch(void* const* d_in, const int* in_sizes, int n_in,
                              void* d_out, int out_size, void* d_ws, size_t ws_size,
                              hipStream_t stream) {
  const float* nodes = (const float*)d_in[0];
  const void*  mask  = d_in[1];
  const float* wq    = (const float*)d_in[2];
  const float* bq    = (const float*)d_in[3];
  const float* wkv   = (const float*)d_in[4];
  const float* bkv   = (const float*)d_in[5];
  const float* wo    = (const float*)d_in[6];
  const float* bo    = (const float*)d_in[7];
  float* out = (float*)d_out;

  char* ws = (char*)d_ws;
  unsigned short* XB    = (unsigned short*)(ws + 0);          //  4 MB  bf16 nodes
  unsigned short* WQKVT = (unsigned short*)(ws + 4194304);    //  1.5MB
  unsigned short* WOT   = (unsigned short*)(ws + 5767168);    //  0.5MB
  unsigned short* Qm    = (unsigned short*)(ws + 6291456);    //  4 MB  [16][2048][64]
  unsigned short* Km    = (unsigned short*)(ws + 10485760);   //  4 MB
  unsigned short* VTm   = (unsigned short*)(ws + 18874368);   //  4 MB  [16][64][2048] s-perm
  unsigned short* AOm   = (unsigned short*)(ws + 23068672);   //  4 MB  [4096][512]
  unsigned int*   PM    = (unsigned int*)(ws + 27262976);     //  1 MB  packed mask (transposed)

  prep_k<<<10624, 256, 0, stream>>>(nodes, mask, wq, wkv, wo, XB, WQKVT, WOT, PM);
  gemm_qkv_k<<<dim3(64, 12), 256, 0, stream>>>(XB, WQKVT, bq, bkv, Qm, Km, VTm);
  attn_k<<<dim3(16, 32), 256, 0, stream>>>(Qm, Km, VTm, PM, AOm);
  gemm_out_k<<<dim3(64, 4), 256, 0, stream>>>(AOm, WOT, bo, out);
}

// Round 8
// 180.996 us; speedup vs baseline: 1.0997x; 1.0997x over previous
//
#include <hip/hip_runtime.h>
#include <cstdint>
#include <cstddef>

#define DEVI __device__ __forceinline__

typedef __bf16 bf16x8 __attribute__((ext_vector_type(8)));
typedef __bf16 bf16x2 __attribute__((ext_vector_type(2)));
typedef float floatx4 __attribute__((ext_vector_type(4)));
typedef unsigned short us4v __attribute__((ext_vector_type(4)));
typedef unsigned short us8 __attribute__((ext_vector_type(8)));

static_assert(sizeof(bf16x8) == 16, "bf16x8 must be 16B");

// ---------------- helpers ----------------

#if __has_builtin(__builtin_amdgcn_cvt_pk_bf16_f32)
DEVI unsigned short f2bf(float f) {
  union { bf16x2 v; unsigned short u[2]; } c;
  c.v = __builtin_amdgcn_cvt_pk_bf16_f32(f, 0.f);
  return c.u[0];
}
DEVI unsigned int pk2bf(float a, float b) {
  union { bf16x2 v; unsigned int u; } c;
  c.v = __builtin_amdgcn_cvt_pk_bf16_f32(a, b);
  return c.u;
}
#else
DEVI unsigned short f2bf(float f) {
  unsigned int u = __float_as_uint(f);
  u += 0x7fffu + ((u >> 16) & 1u);   // RNE
  return (unsigned short)(u >> 16);
}
DEVI unsigned int pk2bf(float a, float b) {
  return (unsigned int)f2bf(a) | ((unsigned int)f2bf(b) << 16);
}
#endif

DEVI float exp2c(float x) {
#if __has_builtin(__builtin_amdgcn_exp2f)
  return __builtin_amdgcn_exp2f(x);
#else
  return exp2f(x);
#endif
}

DEVI bf16x8 ld8(const unsigned short* p) { return *(const bf16x8*)p; }

typedef const __attribute__((address_space(1))) void* gas_ptr;
typedef __attribute__((address_space(3))) void* las_ptr;

DEVI void gld16(const void* g, void* l) {
  __builtin_amdgcn_global_load_lds((gas_ptr)g, (las_ptr)l, 16, 0, 0);
}

#define WAIT_LGKM0() __builtin_amdgcn_s_waitcnt(0xc07f)   // lgkmcnt(0) only

// ---------------- fused prep: mask bitpack + nodes cvt + weight transposes ----------------
// pm layout: pm[((((b*32+qt)*4+qb)*16+it)*4+wave)*16 + l16] covers keys
// (it*4+wave)*32..+31 of q-row qt*64+qb*16+l16 (lane-contiguous 64B per load).
__global__ __launch_bounds__(256) void prep_k(
    const float* __restrict__ nodes, const void* __restrict__ mask,
    const float* __restrict__ wq, const float* __restrict__ wkv,
    const float* __restrict__ wo,
    unsigned short* __restrict__ XB, unsigned short* __restrict__ WQKVT,
    unsigned short* __restrict__ WOT, unsigned int* __restrict__ pm) {
  int bid = blockIdx.x;
  if (bid < 8192) {
    __shared__ int mode;
    const unsigned int* md = (const unsigned int*)mask;
    unsigned int probe = md[threadIdx.x];
    bool odd = (probe > 1u && probe != 0x3f800000u);
    if (threadIdx.x == 0) mode = 0;
    __syncthreads();
    if (odd) atomicOr(&mode, 1);
    __syncthreads();
    int byteMode = mode;
    int t = bid * 256 + threadIdx.x;
    int lane = threadIdx.x & 63;
    unsigned int n;
    if (byteMode) {
      unsigned int x = md[t];
      n = ((x & 0xffu) ? 1u : 0u) | ((x & 0xff00u) ? 2u : 0u) |
          ((x & 0xff0000u) ? 4u : 0u) | ((x >> 24) ? 8u : 0u);
    } else {
      uint4 v = ((const uint4*)mask)[t];
      n = (v.x ? 1u : 0u) | (v.y ? 2u : 0u) | (v.z ? 4u : 0u) | (v.w ? 8u : 0u);
    }
    unsigned int w = n << ((lane & 7) * 4);
    w |= __shfl_xor(w, 1);
    w |= __shfl_xor(w, 2);
    w |= __shfl_xor(w, 4);
    if ((lane & 7) == 0) {
      unsigned int lin = (unsigned int)(t >> 3);   // global word index
      unsigned int q_lin = lin >> 6;               // b*2048+q
      unsigned int word = lin & 63;                // it*4 + wave
      unsigned int b = q_lin >> 11, q = q_lin & 2047;
      unsigned int qt = q >> 6, qb = (q >> 4) & 3, l16 = q & 15;
      unsigned int it = word >> 2, wv = word & 3;
      pm[((((b * 32 + qt) * 4 + qb) * 16 + it) * 4 + wv) * 16 + l16] = w;
    }
  } else if (bid < 10240) {
    int i = (bid - 8192) * 256 + threadIdx.x;
    float4 v = ((const float4*)nodes)[i];
    us4v o;
    o[0] = f2bf(v.x); o[1] = f2bf(v.y); o[2] = f2bf(v.z); o[3] = f2bf(v.w);
    *(us4v*)(XB + (size_t)i * 4) = o;
  } else {
    int tb = bid - 10240;
    int x = tb & 15, y = (tb >> 4) & 7, z = tb >> 7;
    const float* src; unsigned short* dst; int C, c0;
    if (z == 0)      { if (x >= 8) return; src = wq;  dst = WQKVT; C = 512;  c0 = 0; }
    else if (z == 1) { src = wkv; dst = WQKVT; C = 1024; c0 = 512; }
    else             { if (x >= 8) return; src = wo;  dst = WOT;  C = 512;  c0 = 0; }
    __shared__ unsigned short t2[64 * 64];
    const int t = threadIdx.x;
    const int ct = x * 64, rt = y * 64;
    for (int p = 0; p < 4; p++) {
      int kl = p * 16 + (t >> 4);
      int cc = (t & 15) * 4;
      float4 v = *(const float4*)&src[(size_t)(rt + kl) * C + ct + cc];
      float f[4] = {v.x, v.y, v.z, v.w};
      for (int i = 0; i < 4; i++) {
        int c = cc + i;
        t2[c * 64 + (kl ^ (c & 56))] = f2bf(f[i]);
      }
    }
    __syncthreads();
    for (int p = 0; p < 2; p++) {
      int c = p * 32 + (t >> 3);
      int kc = (t & 7) * 8;
      us8 v = *(const us8*)&t2[c * 64 + (kc ^ (c & 56))];
      *(us8*)&dst[(size_t)(c0 + ct + c) * 512 + rt + kc] = v;
    }
  }
}

// ---------------- QKV GEMM: 64x128 tiles, double-buffered, grid (64,12) ----------------
__global__ __launch_bounds__(256) void gemm_qkv_k(
    const unsigned short* __restrict__ A,    // [4096][512]
    const unsigned short* __restrict__ Bt,   // [1536][512]
    const float* __restrict__ bq, const float* __restrict__ bkv,
    unsigned short* __restrict__ Qo, unsigned short* __restrict__ Ko,
    unsigned short* __restrict__ VTo) {
  __shared__ unsigned short smem[12288];     // 24 KB: 2 bufs x (sA 2048 + sB 4096)
  const int tid = threadIdx.x;
  const int wave = tid >> 6, lane = tid & 63, quad = lane >> 4, l16 = lane & 15;
  const int wm = wave >> 1, wn = wave & 1;
  const int bm = blockIdx.x, bn = blockIdx.y;
  floatx4 acc[2][4] = {};
  const int arow = lane >> 2;
  const int ag = lane & 3;

  auto stage = [&](int kt, int buf) {
    unsigned short* sA = smem + buf * 6144;
    unsigned short* sB = sA + 2048;
    int rowA = wave * 16 + arow;
    int gA = ag ^ (rowA & 3);
    gld16(&A[(size_t)(bm * 64 + rowA) * 512 + kt * 32 + gA * 8], &sA[(wave * 16) * 32]);
    for (int p = 0; p < 2; p++) {
      int rowB = p * 64 + wave * 16 + arow;
      int gB = ag ^ (rowB & 3);
      gld16(&Bt[(size_t)(bn * 128 + rowB) * 512 + kt * 32 + gB * 8],
            &sB[(p * 64 + wave * 16) * 32]);
    }
  };

  stage(0, 0);
  for (int kt = 0; kt < 16; kt++) {
    __syncthreads();                          // drains vmcnt: buf[kt&1] ready
    if (kt + 1 < 16) stage(kt + 1, (kt + 1) & 1);
    const unsigned short* sA = smem + (kt & 1) * 6144;
    const unsigned short* sB = sA + 2048;
    bf16x8 aF[2], bF[4];
    int swz = (quad ^ (l16 & 3)) * 8;
    for (int i = 0; i < 2; i++) aF[i] = ld8(&sA[(wm * 32 + i * 16 + l16) * 32 + swz]);
    for (int j = 0; j < 4; j++) bF[j] = ld8(&sB[(wn * 64 + j * 16 + l16) * 32 + swz]);
    for (int i = 0; i < 2; i++)
      for (int j = 0; j < 4; j++)
        acc[i][j] = __builtin_amdgcn_mfma_f32_16x16x32_bf16(aF[i], bF[j], acc[i][j], 0, 0, 0);
  }

  const int sec = bn * 2 + wn;               // 0..23: Q heads 0-7, K 8-15, V 16-23
  float bias[4];
  float scale = 1.0f;
  if (sec < 8) {
    for (int j = 0; j < 4; j++) bias[j] = bq[sec * 64 + j * 16 + l16];
    scale = 0.18033688011112042f;            // 0.125 * log2(e)
  } else {
    for (int j = 0; j < 4; j++) bias[j] = bkv[(sec - 8) * 64 + j * 16 + l16];
  }
  const int gr0 = bm * 64 + wm * 32;
  const int b = gr0 >> 11, n0 = gr0 & 2047;
  unsigned short* pw = smem + wave * 2048;
  __syncthreads();
  if (sec < 16) {
    for (int i = 0; i < 2; i++)
      for (int j = 0; j < 4; j++) {
        int cg = j * 2 + (l16 >> 3), ci = l16 & 7;
        for (int r = 0; r < 4; r++) {
          int row = i * 16 + quad * 4 + r;
          pw[row * 64 + ((cg ^ (row & 7)) * 8) + ci] = f2bf((acc[i][j][r] + bias[j]) * scale);
        }
      }
    WAIT_LGKM0();
    unsigned short* dst = (sec < 8) ? Qo + ((size_t)(b * 8 + sec) * 2048 + n0) * 64
                                    : Ko + ((size_t)(b * 8 + sec - 8) * 2048 + n0) * 64;
    for (int p = 0; p < 4; p++) {
      int row = p * 8 + (lane >> 3);
      int c8 = lane & 7;
      us8 v = *(const us8*)&pw[row * 64 + ((c8 ^ (row & 7)) * 8)];
      *(us8*)&dst[(size_t)row * 64 + c8 * 8] = v;
    }
  } else {
    // V: [64 d][32 n], keys s-permuted per 32-block: s = quad*8 + i*4 + r
    for (int i = 0; i < 2; i++)
      for (int j = 0; j < 4; j++) {
        int d = j * 16 + l16;
        us4v t;
        for (int r = 0; r < 4; r++) t[r] = f2bf(acc[i][j][r] + bias[j]);
        *(us4v*)&pw[d * 32 + ((quad ^ (d & 3)) * 8) + i * 4] = t;
      }
    WAIT_LGKM0();
    unsigned short* dst = VTo + (size_t)(b * 8 + sec - 16) * 64 * 2048 + n0;
    for (int p = 0; p < 4; p++) {
      int d = p * 16 + (lane >> 2);
      int c4 = lane & 3;
      us8 v = *(const us8*)&pw[d * 32 + ((c4 ^ (d & 3)) * 8)];
      *(us8*)&dst[(size_t)d * 2048 + c4 * 8] = v;
    }
  }
}

// ---------------- flash attention (barrier-free, register-pipelined) ----------------
// 4 waves, 64 q shared; wave owns 32-key slice per iter (128 keys/block-iter,
// 16 iters). All operands global->VGPR, explicitly double-buffered across
// iterations so the compiler emits fine-grained vmcnt waits (no barriers, no
// LDS in the loop). launch_bounds(256,2): 256-reg budget -> no spills.
__global__ __launch_bounds__(256, 2) void attn_k(
    const unsigned short* __restrict__ Q,    // [16][2048][64], pre-scaled
    const unsigned short* __restrict__ K,    // [16][2048][64]
    const unsigned short* __restrict__ Vt,   // [16][64][2048] s-permuted
    const unsigned int* __restrict__ pm,     // [b][qt][qb][it][wave][l16] packed mask
    unsigned short* __restrict__ AO) {       // [2][2048][512]
  __shared__ float Ored[4096];               // 16 KB [64q][64d] swizzled
  __shared__ float lsumB[4][64];
  const int tid = threadIdx.x;
  const int wave = tid >> 6, lane = tid & 63, quad = lane >> 4, l16 = lane & 15;
  const int bh = blockIdx.x, qt = blockIdx.y, b = bh >> 3, h = bh & 7;
  const int q0 = qt * 64;
  const unsigned short* Qb = Q + (size_t)bh * 2048 * 64;
  const unsigned short* Kb = K + (size_t)bh * 2048 * 64;
  const unsigned short* Vb = Vt + (size_t)bh * 64 * 2048;

  bf16x8 qF[4][2];
  for (int qb = 0; qb < 4; qb++) {
    qF[qb][0] = ld8(&Qb[(size_t)(q0 + qb * 16 + l16) * 64 + quad * 8]);
    qF[qb][1] = ld8(&Qb[(size_t)(q0 + qb * 16 + l16) * 64 + 32 + quad * 8]);
  }

  // mask bases: lane-contiguous 64B per (qb,it)
  const unsigned int* mp[4];
  for (int qb = 0; qb < 4; qb++)
    mp[qb] = pm + ((size_t)((b * 32 + qt) * 4 + qb) * 1024) + wave * 16 + l16;

  floatx4 oacc[4][4] = {};                   // [db][qb]
  float lsum[4] = {0.f, 0.f, 0.f, 0.f};

  bf16x8 kf[2][4];                           // [buf][k2*2 + hi]
  bf16x8 va[2][4];                           // [buf][db]
  unsigned int mw[2][4];                     // [buf][qb]

  auto LD = [&](int t, int bf) {
    const int k0w = t * 128 + wave * 32;
    for (int k2 = 0; k2 < 2; k2++) {
      const unsigned short* kr = &Kb[(size_t)(k0w + k2 * 16 + l16) * 64 + quad * 8];
      kf[bf][k2 * 2]     = ld8(kr);
      kf[bf][k2 * 2 + 1] = ld8(kr + 32);
    }
    for (int db = 0; db < 4; db++)
      va[bf][db] = ld8(&Vb[(size_t)(db * 16 + l16) * 2048 + k0w + quad * 8]);
    for (int qb = 0; qb < 4; qb++) mw[bf][qb] = mp[qb][t * 64];
  };

  LD(0, 0);
#pragma unroll
  for (int it = 0; it < 16; ++it) {
    const int cur = it & 1;
    if (it + 1 < 16) LD(it + 1, cur ^ 1);

    union uB { bf16x8 v; unsigned int d[4]; } pf[4];
    for (int k2 = 0; k2 < 2; k2++) {
      floatx4 st[4];
      for (int qb = 0; qb < 4; qb++) {
        floatx4 z = {0.f, 0.f, 0.f, 0.f};
        z = __builtin_amdgcn_mfma_f32_16x16x32_bf16(kf[cur][k2 * 2], qF[qb][0], z, 0, 0, 0);
        st[qb] = __builtin_amdgcn_mfma_f32_16x16x32_bf16(kf[cur][k2 * 2 + 1], qF[qb][1], z, 0, 0, 0);
      }
      for (int qb = 0; qb < 4; qb++) {
        unsigned int w = mw[cur][qb];
        int base = k2 * 16 + quad * 4;
        float e0 = exp2c(st[qb][0]); e0 = ((w >> (base + 0)) & 1u) ? e0 : 0.f;
        float e1 = exp2c(st[qb][1]); e1 = ((w >> (base + 1)) & 1u) ? e1 : 0.f;
        float e2 = exp2c(st[qb][2]); e2 = ((w >> (base + 2)) & 1u) ? e2 : 0.f;
        float e3 = exp2c(st[qb][3]); e3 = ((w >> (base + 3)) & 1u) ? e3 : 0.f;
        lsum[qb] += (e0 + e1) + (e2 + e3);
        pf[qb].d[k2 * 2]     = pk2bf(e0, e1);
        pf[qb].d[k2 * 2 + 1] = pk2bf(e2, e3);
      }
    }

    for (int db = 0; db < 4; db++)
      for (int qb = 0; qb < 4; qb++)
        oacc[db][qb] =
            __builtin_amdgcn_mfma_f32_16x16x32_bf16(va[cur][db], pf[qb].v, oacc[db][qb], 0, 0, 0);
  }

  // lsum: reduce across quads; lane(quad,l16) publishes q = quad*16+l16
  for (int qb = 0; qb < 4; qb++) {
    lsum[qb] += __shfl_xor(lsum[qb], 16);
    lsum[qb] += __shfl_xor(lsum[qb], 32);
  }
  lsumB[wave][quad * 16 + l16] = lsum[quad];

  // split-K reduction: 4 sequential read-add rounds into Ored (swizzled)
  for (int w = 0; w < 4; w++) {
    if (wave == w) {
      for (int db = 0; db < 4; db++)
        for (int qb = 0; qb < 4; qb++) {
          int q = qb * 16 + l16;
          int off = q * 64 + (((db * 4 + quad) ^ l16) & 15) * 4;
          if (w == 0) {
            *(floatx4*)&Ored[off] = oacc[db][qb];
          } else {
            floatx4 t = *(floatx4*)&Ored[off];
            t += oacc[db][qb];
            *(floatx4*)&Ored[off] = t;
          }
        }
    }
    __syncthreads();
  }

  {
    int q = tid >> 2, dblk = tid & 3;
    float inv = 1.0f / (lsumB[0][q] + lsumB[1][q] + lsumB[2][q] + lsumB[3][q]);
    float o[16];
    for (int i = 0; i < 4; i++) {
      int dg = dblk * 4 + i;
      int off = q * 64 + ((dg ^ q) & 15) * 4;
      floatx4 s = *(floatx4*)&Ored[off];
      for (int r = 0; r < 4; r++) o[i * 4 + r] = s[r] * inv;
    }
    us8 v0, v1;
    for (int i = 0; i < 8; i++) { v0[i] = f2bf(o[i]); v1[i] = f2bf(o[8 + i]); }
    unsigned short* dst = &AO[((size_t)b * 2048 + q0 + q) * 512 + h * 64 + dblk * 16];
    *(us8*)dst = v0;
    *(us8*)(dst + 8) = v1;
  }
}

// ---------------- out GEMM: 64x128 tiles, double-buffered, grid (64,4) ----------------
__global__ __launch_bounds__(256) void gemm_out_k(
    const unsigned short* __restrict__ A,    // [4096][512]
    const unsigned short* __restrict__ Bt,   // [512][512]
    const float* __restrict__ bo, float* __restrict__ out) {
  __shared__ unsigned short smem[12288];
  const int tid = threadIdx.x;
  const int wave = tid >> 6, lane = tid & 63, quad = lane >> 4, l16 = lane & 15;
  const int wm = wave >> 1, wn = wave & 1;
  const int bm = blockIdx.x, bn = blockIdx.y;
  floatx4 acc[2][4] = {};
  const int arow = lane >> 2;
  const int ag = lane & 3;

  auto stage = [&](int kt, int buf) {
    unsigned short* sA = smem + buf * 6144;
    unsigned short* sB = sA + 2048;
    int rowA = wave * 16 + arow;
    int gA = ag ^ (rowA & 3);
    gld16(&A[(size_t)(bm * 64 + rowA) * 512 + kt * 32 + gA * 8], &sA[(wave * 16) * 32]);
    for (int p = 0; p < 2; p++) {
      int rowB = p * 64 + wave * 16 + arow;
      int gB = ag ^ (rowB & 3);
      gld16(&Bt[(size_t)(bn * 128 + rowB) * 512 + kt * 32 + gB * 8],
            &sB[(p * 64 + wave * 16) * 32]);
    }
  };

  stage(0, 0);
  for (int kt = 0; kt < 16; kt++) {
    __syncthreads();
    if (kt + 1 < 16) stage(kt + 1, (kt + 1) & 1);
    const unsigned short* sA = smem + (kt & 1) * 6144;
    const unsigned short* sB = sA + 2048;
    bf16x8 aF[2], bF[4];
    int swz = (quad ^ (l16 & 3)) * 8;
    for (int i = 0; i < 2; i++) aF[i] = ld8(&sA[(wm * 32 + i * 16 + l16) * 32 + swz]);
    for (int j = 0; j < 4; j++) bF[j] = ld8(&sB[(wn * 64 + j * 16 + l16) * 32 + swz]);
    for (int i = 0; i < 2; i++)
      for (int j = 0; j < 4; j++)
        acc[i][j] = __builtin_amdgcn_mfma_f32_16x16x32_bf16(aF[i], bF[j], acc[i][j], 0, 0, 0);
  }
  for (int i = 0; i < 2; i++)
    for (int j = 0; j < 4; j++) {
      int gc = bn * 128 + wn * 64 + j * 16 + l16;
      float bb = bo[gc];
      for (int r = 0; r < 4; r++) {
        int gr = bm * 64 + wm * 32 + i * 16 + quad * 4 + r;
        out[(size_t)gr * 512 + gc] = acc[i][j][r] + bb;
      }
    }
}

// ---------------- launch ----------------
extern "C" void kernel_launch(void* const* d_in, const int* in_sizes, int n_in,
                              void* d_out, int out_size, void* d_ws, size_t ws_size,
                              hipStream_t stream) {
  const float* nodes = (const float*)d_in[0];
  const void*  mask  = d_in[1];
  const float* wq    = (const float*)d_in[2];
  const float* bq    = (const float*)d_in[3];
  const float* wkv   = (const float*)d_in[4];
  const float* bkv   = (const float*)d_in[5];
  const float* wo    = (const float*)d_in[6];
  const float* bo    = (const float*)d_in[7];
  float* out = (float*)d_out;

  char* ws = (char*)d_ws;
  unsigned short* XB    = (unsigned short*)(ws + 0);          //  4 MB  bf16 nodes
  unsigned short* WQKVT = (unsigned short*)(ws + 4194304);    //  1.5MB
  unsigned short* WOT   = (unsigned short*)(ws + 5767168);    //  0.5MB
  unsigned short* Qm    = (unsigned short*)(ws + 6291456);    //  4 MB  [16][2048][64]
  unsigned short* Km    = (unsigned short*)(ws + 10485760);   //  4 MB
  unsigned short* VTm   = (unsigned short*)(ws + 18874368);   //  4 MB  [16][64][2048] s-perm
  unsigned short* AOm   = (unsigned short*)(ws + 23068672);   //  4 MB  [4096][512]
  unsigned int*   PM    = (unsigned int*)(ws + 27262976);     //  1 MB  packed mask

  prep_k<<<10624, 256, 0, stream>>>(nodes, mask, wq, wkv, wo, XB, WQKVT, WOT, PM);
  gemm_qkv_k<<<dim3(64, 12), 256, 0, stream>>>(XB, WQKVT, bq, bkv, Qm, Km, VTm);
  attn_k<<<dim3(16, 32), 256, 0, stream>>>(Qm, Km, VTm, PM, AOm);
  gemm_out_k<<<dim3(64, 4), 256, 0, stream>>>(AOm, WOT, bo, out);
}

// Round 9
// 154.049 us; speedup vs baseline: 1.2921x; 1.1749x over previous
//
#include <hip/hip_runtime.h>
#include <cstdint>
#include <cstddef>

#define DEVI __device__ __forceinline__

typedef __bf16 bf16x8 __attribute__((ext_vector_type(8)));
typedef __bf16 bf16x2 __attribute__((ext_vector_type(2)));
typedef float floatx4 __attribute__((ext_vector_type(4)));
typedef unsigned short us4v __attribute__((ext_vector_type(4)));
typedef unsigned short us8 __attribute__((ext_vector_type(8)));

static_assert(sizeof(bf16x8) == 16, "bf16x8 must be 16B");

// ---------------- helpers ----------------

#if __has_builtin(__builtin_amdgcn_cvt_pk_bf16_f32)
DEVI unsigned short f2bf(float f) {
  union { bf16x2 v; unsigned short u[2]; } c;
  c.v = __builtin_amdgcn_cvt_pk_bf16_f32(f, 0.f);
  return c.u[0];
}
DEVI unsigned int pk2bf(float a, float b) {
  union { bf16x2 v; unsigned int u; } c;
  c.v = __builtin_amdgcn_cvt_pk_bf16_f32(a, b);
  return c.u;
}
#else
DEVI unsigned short f2bf(float f) {
  unsigned int u = __float_as_uint(f);
  u += 0x7fffu + ((u >> 16) & 1u);   // RNE
  return (unsigned short)(u >> 16);
}
DEVI unsigned int pk2bf(float a, float b) {
  return (unsigned int)f2bf(a) | ((unsigned int)f2bf(b) << 16);
}
#endif

DEVI float exp2c(float x) {
#if __has_builtin(__builtin_amdgcn_exp2f)
  return __builtin_amdgcn_exp2f(x);
#else
  return exp2f(x);
#endif
}

DEVI bf16x8 ld8(const unsigned short* p) { return *(const bf16x8*)p; }

typedef const __attribute__((address_space(1))) void* gas_ptr;
typedef __attribute__((address_space(3))) void* las_ptr;

DEVI void gld16(const void* g, void* l) {
  __builtin_amdgcn_global_load_lds((gas_ptr)g, (las_ptr)l, 16, 0, 0);
}

#define WAIT_LGKM0() __builtin_amdgcn_s_waitcnt(0xc07f)   // lgkmcnt(0) only

// ---------------- fused prep: mask bitpack + nodes cvt + weight transposes ----------------
// pm layout: pm[((((b*32+qt)*4+qb)*16+it)*4+wave)*16 + l16] covers keys
// (it*4+wave)*32..+31 of q-row qt*64+qb*16+l16 (lane-contiguous 64B per load).
__global__ __launch_bounds__(256) void prep_k(
    const float* __restrict__ nodes, const void* __restrict__ mask,
    const float* __restrict__ wq, const float* __restrict__ wkv,
    const float* __restrict__ wo,
    unsigned short* __restrict__ XB, unsigned short* __restrict__ WQKVT,
    unsigned short* __restrict__ WOT, unsigned int* __restrict__ pm) {
  int bid = blockIdx.x;
  if (bid < 8192) {
    __shared__ int mode;
    const unsigned int* md = (const unsigned int*)mask;
    unsigned int probe = md[threadIdx.x];
    bool odd = (probe > 1u && probe != 0x3f800000u);
    if (threadIdx.x == 0) mode = 0;
    __syncthreads();
    if (odd) atomicOr(&mode, 1);
    __syncthreads();
    int byteMode = mode;
    int t = bid * 256 + threadIdx.x;
    int lane = threadIdx.x & 63;
    unsigned int n;
    if (byteMode) {
      unsigned int x = md[t];
      n = ((x & 0xffu) ? 1u : 0u) | ((x & 0xff00u) ? 2u : 0u) |
          ((x & 0xff0000u) ? 4u : 0u) | ((x >> 24) ? 8u : 0u);
    } else {
      uint4 v = ((const uint4*)mask)[t];
      n = (v.x ? 1u : 0u) | (v.y ? 2u : 0u) | (v.z ? 4u : 0u) | (v.w ? 8u : 0u);
    }
    unsigned int w = n << ((lane & 7) * 4);
    w |= __shfl_xor(w, 1);
    w |= __shfl_xor(w, 2);
    w |= __shfl_xor(w, 4);
    if ((lane & 7) == 0) {
      unsigned int lin = (unsigned int)(t >> 3);   // global word index
      unsigned int q_lin = lin >> 6;               // b*2048+q
      unsigned int word = lin & 63;                // it*4 + wave
      unsigned int b = q_lin >> 11, q = q_lin & 2047;
      unsigned int qt = q >> 6, qb = (q >> 4) & 3, l16 = q & 15;
      unsigned int it = word >> 2, wv = word & 3;
      pm[((((b * 32 + qt) * 4 + qb) * 16 + it) * 4 + wv) * 16 + l16] = w;
    }
  } else if (bid < 10240) {
    int i = (bid - 8192) * 256 + threadIdx.x;
    float4 v = ((const float4*)nodes)[i];
    us4v o;
    o[0] = f2bf(v.x); o[1] = f2bf(v.y); o[2] = f2bf(v.z); o[3] = f2bf(v.w);
    *(us4v*)(XB + (size_t)i * 4) = o;
  } else {
    int tb = bid - 10240;
    int x = tb & 15, y = (tb >> 4) & 7, z = tb >> 7;
    const float* src; unsigned short* dst; int C, c0;
    if (z == 0)      { if (x >= 8) return; src = wq;  dst = WQKVT; C = 512;  c0 = 0; }
    else if (z == 1) { src = wkv; dst = WQKVT; C = 1024; c0 = 512; }
    else             { if (x >= 8) return; src = wo;  dst = WOT;  C = 512;  c0 = 0; }
    __shared__ unsigned short t2[64 * 64];
    const int t = threadIdx.x;
    const int ct = x * 64, rt = y * 64;
    for (int p = 0; p < 4; p++) {
      int kl = p * 16 + (t >> 4);
      int cc = (t & 15) * 4;
      float4 v = *(const float4*)&src[(size_t)(rt + kl) * C + ct + cc];
      float f[4] = {v.x, v.y, v.z, v.w};
      for (int i = 0; i < 4; i++) {
        int c = cc + i;
        t2[c * 64 + (kl ^ (c & 56))] = f2bf(f[i]);
      }
    }
    __syncthreads();
    for (int p = 0; p < 2; p++) {
      int c = p * 32 + (t >> 3);
      int kc = (t & 7) * 8;
      us8 v = *(const us8*)&t2[c * 64 + (kc ^ (c & 56))];
      *(us8*)&dst[(size_t)(c0 + ct + c) * 512 + rt + kc] = v;
    }
  }
}

// ---------------- QKV GEMM: 64x128 tiles, double-buffered, grid (64,12) ----------------
__global__ __launch_bounds__(256) void gemm_qkv_k(
    const unsigned short* __restrict__ A,    // [4096][512]
    const unsigned short* __restrict__ Bt,   // [1536][512]
    const float* __restrict__ bq, const float* __restrict__ bkv,
    unsigned short* __restrict__ Qo, unsigned short* __restrict__ Ko,
    unsigned short* __restrict__ VTo) {
  __shared__ unsigned short smem[12288];     // 24 KB: 2 bufs x (sA 2048 + sB 4096)
  const int tid = threadIdx.x;
  const int wave = tid >> 6, lane = tid & 63, quad = lane >> 4, l16 = lane & 15;
  const int wm = wave >> 1, wn = wave & 1;
  const int bm = blockIdx.x, bn = blockIdx.y;
  floatx4 acc[2][4] = {};
  const int arow = lane >> 2;
  const int ag = lane & 3;

  auto stage = [&](int kt, int buf) {
    unsigned short* sA = smem + buf * 6144;
    unsigned short* sB = sA + 2048;
    int rowA = wave * 16 + arow;
    int gA = ag ^ (rowA & 3);
    gld16(&A[(size_t)(bm * 64 + rowA) * 512 + kt * 32 + gA * 8], &sA[(wave * 16) * 32]);
    for (int p = 0; p < 2; p++) {
      int rowB = p * 64 + wave * 16 + arow;
      int gB = ag ^ (rowB & 3);
      gld16(&Bt[(size_t)(bn * 128 + rowB) * 512 + kt * 32 + gB * 8],
            &sB[(p * 64 + wave * 16) * 32]);
    }
  };

  stage(0, 0);
  for (int kt = 0; kt < 16; kt++) {
    __syncthreads();                          // drains vmcnt: buf[kt&1] ready
    if (kt + 1 < 16) stage(kt + 1, (kt + 1) & 1);
    const unsigned short* sA = smem + (kt & 1) * 6144;
    const unsigned short* sB = sA + 2048;
    bf16x8 aF[2], bF[4];
    int swz = (quad ^ (l16 & 3)) * 8;
    for (int i = 0; i < 2; i++) aF[i] = ld8(&sA[(wm * 32 + i * 16 + l16) * 32 + swz]);
    for (int j = 0; j < 4; j++) bF[j] = ld8(&sB[(wn * 64 + j * 16 + l16) * 32 + swz]);
    for (int i = 0; i < 2; i++)
      for (int j = 0; j < 4; j++)
        acc[i][j] = __builtin_amdgcn_mfma_f32_16x16x32_bf16(aF[i], bF[j], acc[i][j], 0, 0, 0);
  }

  const int sec = bn * 2 + wn;               // 0..23: Q heads 0-7, K 8-15, V 16-23
  float bias[4];
  float scale = 1.0f;
  if (sec < 8) {
    for (int j = 0; j < 4; j++) bias[j] = bq[sec * 64 + j * 16 + l16];
    scale = 0.18033688011112042f;            // 0.125 * log2(e)
  } else {
    for (int j = 0; j < 4; j++) bias[j] = bkv[(sec - 8) * 64 + j * 16 + l16];
  }
  const int gr0 = bm * 64 + wm * 32;
  const int b = gr0 >> 11, n0 = gr0 & 2047;
  unsigned short* pw = smem + wave * 2048;
  __syncthreads();
  if (sec < 16) {
    for (int i = 0; i < 2; i++)
      for (int j = 0; j < 4; j++) {
        int cg = j * 2 + (l16 >> 3), ci = l16 & 7;
        for (int r = 0; r < 4; r++) {
          int row = i * 16 + quad * 4 + r;
          pw[row * 64 + ((cg ^ (row & 7)) * 8) + ci] = f2bf((acc[i][j][r] + bias[j]) * scale);
        }
      }
    WAIT_LGKM0();
    unsigned short* dst = (sec < 8) ? Qo + ((size_t)(b * 8 + sec) * 2048 + n0) * 64
                                    : Ko + ((size_t)(b * 8 + sec - 8) * 2048 + n0) * 64;
    for (int p = 0; p < 4; p++) {
      int row = p * 8 + (lane >> 3);
      int c8 = lane & 7;
      us8 v = *(const us8*)&pw[row * 64 + ((c8 ^ (row & 7)) * 8)];
      *(us8*)&dst[(size_t)row * 64 + c8 * 8] = v;
    }
  } else {
    // V: [64 d][32 n], keys s-permuted per 32-block: s = quad*8 + i*4 + r
    for (int i = 0; i < 2; i++)
      for (int j = 0; j < 4; j++) {
        int d = j * 16 + l16;
        us4v t;
        for (int r = 0; r < 4; r++) t[r] = f2bf(acc[i][j][r] + bias[j]);
        *(us4v*)&pw[d * 32 + ((quad ^ (d & 3)) * 8) + i * 4] = t;
      }
    WAIT_LGKM0();
    unsigned short* dst = VTo + (size_t)(b * 8 + sec - 16) * 64 * 2048 + n0;
    for (int p = 0; p < 4; p++) {
      int d = p * 16 + (lane >> 2);
      int c4 = lane & 3;
      us8 v = *(const us8*)&pw[d * 32 + ((c4 ^ (d & 3)) * 8)];
      *(us8*)&dst[(size_t)d * 2048 + c4 * 8] = v;
    }
  }
}

// ---------------- flash attention (barrier-free, single-buffered early-issue) ----------------
// 4 waves, 64 q shared; wave owns a 32-key slice per iter (128 keys/block-iter,
// 16 iters). Operands global->VGPR; next-iter load issued right after last use
// this iter (load->use distance ~ one compute phase hides L2 latency). No
// barriers / LDS in loop. Plain launch_bounds(256): allocator free, no spills.
__global__ __launch_bounds__(256) void attn_k(
    const unsigned short* __restrict__ Q,    // [16][2048][64], pre-scaled
    const unsigned short* __restrict__ K,    // [16][2048][64]
    const unsigned short* __restrict__ Vt,   // [16][64][2048] s-permuted
    const unsigned int* __restrict__ pm,     // [b][qt][qb][it][wave][l16] packed mask
    unsigned short* __restrict__ AO) {       // [2][2048][512]
  __shared__ float Ored[4096];               // 16 KB [64q][64d] swizzled
  __shared__ float lsumB[4][64];
  const int tid = threadIdx.x;
  const int wave = tid >> 6, lane = tid & 63, quad = lane >> 4, l16 = lane & 15;
  const int bh = blockIdx.x, qt = blockIdx.y, b = bh >> 3, h = bh & 7;
  const int q0 = qt * 64;
  const unsigned short* Qb = Q + (size_t)bh * 131072;
  const unsigned short* Kb = K + (size_t)bh * 131072;
  const unsigned short* Vb = Vt + (size_t)bh * 131072;

  bf16x8 qF[4][2];
  for (int qb = 0; qb < 4; qb++) {
    qF[qb][0] = ld8(&Qb[(size_t)(q0 + qb * 16 + l16) * 64 + quad * 8]);
    qF[qb][1] = ld8(&Qb[(size_t)(q0 + qb * 16 + l16) * 64 + 32 + quad * 8]);
  }

  const unsigned short* kp = Kb + ((wave * 32 + l16) << 6) + quad * 8;
  const unsigned short* vp = Vb + (l16 << 11) + wave * 32 + quad * 8;
  const unsigned int* mp = pm + (size_t)((b * 32 + qt) * 4) * 1024 + wave * 16 + l16;

  floatx4 oacc[4][4] = {};                   // [db][qb]
  float lsum[4] = {0.f, 0.f, 0.f, 0.f};

  bf16x8 kf[4], va[4];
  unsigned int mw[4];
  kf[0] = ld8(kp); kf[1] = ld8(kp + 32);
  kf[2] = ld8(kp + 1024); kf[3] = ld8(kp + 1056);
  for (int db = 0; db < 4; db++) va[db] = ld8(vp + db * 32768);
  for (int qb = 0; qb < 4; qb++) mw[qb] = mp[qb * 1024];

  auto iter = [&](int it, bool more) {
    const unsigned short* kpn = kp + 8192;
    const unsigned short* vpn = vp + 128;
    union uB { bf16x8 v; unsigned int d[4]; } pf[4];
    floatx4 st[4];

    // ---- k2 = 0: keys k0w .. k0w+15 ----
    for (int qb = 0; qb < 4; qb++) {
      floatx4 z = {0.f, 0.f, 0.f, 0.f};
      z = __builtin_amdgcn_mfma_f32_16x16x32_bf16(kf[0], qF[qb][0], z, 0, 0, 0);
      st[qb] = __builtin_amdgcn_mfma_f32_16x16x32_bf16(kf[1], qF[qb][1], z, 0, 0, 0);
    }
    if (more) { kf[0] = ld8(kpn); kf[1] = ld8(kpn + 32); }
    for (int qb = 0; qb < 4; qb++) {
      unsigned int w = mw[qb] >> (quad * 4);
      float e0 = exp2c(st[qb][0]); e0 = (w & 1u) ? e0 : 0.f;
      float e1 = exp2c(st[qb][1]); e1 = (w & 2u) ? e1 : 0.f;
      float e2 = exp2c(st[qb][2]); e2 = (w & 4u) ? e2 : 0.f;
      float e3 = exp2c(st[qb][3]); e3 = (w & 8u) ? e3 : 0.f;
      lsum[qb] += (e0 + e1) + (e2 + e3);
      pf[qb].d[0] = pk2bf(e0, e1);
      pf[qb].d[1] = pk2bf(e2, e3);
    }

    // ---- k2 = 1: keys k0w+16 .. k0w+31 ----
    for (int qb = 0; qb < 4; qb++) {
      floatx4 z = {0.f, 0.f, 0.f, 0.f};
      z = __builtin_amdgcn_mfma_f32_16x16x32_bf16(kf[2], qF[qb][0], z, 0, 0, 0);
      st[qb] = __builtin_amdgcn_mfma_f32_16x16x32_bf16(kf[3], qF[qb][1], z, 0, 0, 0);
    }
    if (more) { kf[2] = ld8(kpn + 1024); kf[3] = ld8(kpn + 1056); }
    for (int qb = 0; qb < 4; qb++) {
      unsigned int w = (mw[qb] >> 16) >> (quad * 4);
      float e0 = exp2c(st[qb][0]); e0 = (w & 1u) ? e0 : 0.f;
      float e1 = exp2c(st[qb][1]); e1 = (w & 2u) ? e1 : 0.f;
      float e2 = exp2c(st[qb][2]); e2 = (w & 4u) ? e2 : 0.f;
      float e3 = exp2c(st[qb][3]); e3 = (w & 8u) ? e3 : 0.f;
      lsum[qb] += (e0 + e1) + (e2 + e3);
      pf[qb].d[2] = pk2bf(e0, e1);
      pf[qb].d[3] = pk2bf(e2, e3);
    }
    if (more)
      for (int qb = 0; qb < 4; qb++) mw[qb] = mp[qb * 1024 + (it + 1) * 64];

    // ---- PV ----
    for (int db = 0; db < 4; db++)
      for (int qb = 0; qb < 4; qb++)
        oacc[db][qb] =
            __builtin_amdgcn_mfma_f32_16x16x32_bf16(va[db], pf[qb].v, oacc[db][qb], 0, 0, 0);
    if (more)
      for (int db = 0; db < 4; db++) va[db] = ld8(vpn + db * 32768);

    kp = kpn;
    vp = vpn;
  };

  for (int it = 0; it < 15; ++it) iter(it, true);
  iter(15, false);

  // lsum: reduce across quads; lane(quad,l16) publishes q = quad*16+l16
  for (int qb = 0; qb < 4; qb++) {
    lsum[qb] += __shfl_xor(lsum[qb], 16);
    lsum[qb] += __shfl_xor(lsum[qb], 32);
  }
  lsumB[wave][quad * 16 + l16] = lsum[quad];

  // split-K reduction: 4 sequential read-add rounds into Ored (swizzled)
  for (int w = 0; w < 4; w++) {
    if (wave == w) {
      for (int db = 0; db < 4; db++)
        for (int qb = 0; qb < 4; qb++) {
          int q = qb * 16 + l16;
          int off = q * 64 + (((db * 4 + quad) ^ l16) & 15) * 4;
          if (w == 0) {
            *(floatx4*)&Ored[off] = oacc[db][qb];
          } else {
            floatx4 t = *(floatx4*)&Ored[off];
            t += oacc[db][qb];
            *(floatx4*)&Ored[off] = t;
          }
        }
    }
    __syncthreads();
  }

  {
    int q = tid >> 2, dblk = tid & 3;
    float inv = 1.0f / (lsumB[0][q] + lsumB[1][q] + lsumB[2][q] + lsumB[3][q]);
    float o[16];
    for (int i = 0; i < 4; i++) {
      int dg = dblk * 4 + i;
      int off = q * 64 + ((dg ^ q) & 15) * 4;
      floatx4 s = *(floatx4*)&Ored[off];
      for (int r = 0; r < 4; r++) o[i * 4 + r] = s[r] * inv;
    }
    us8 v0, v1;
    for (int i = 0; i < 8; i++) { v0[i] = f2bf(o[i]); v1[i] = f2bf(o[8 + i]); }
    unsigned short* dst = &AO[((size_t)b * 2048 + q0 + q) * 512 + h * 64 + dblk * 16];
    *(us8*)dst = v0;
    *(us8*)(dst + 8) = v1;
  }
}

// ---------------- out GEMM: 64x128 tiles, double-buffered, grid (64,4) ----------------
__global__ __launch_bounds__(256) void gemm_out_k(
    const unsigned short* __restrict__ A,    // [4096][512]
    const unsigned short* __restrict__ Bt,   // [512][512]
    const float* __restrict__ bo, float* __restrict__ out) {
  __shared__ unsigned short smem[12288];
  const int tid = threadIdx.x;
  const int wave = tid >> 6, lane = tid & 63, quad = lane >> 4, l16 = lane & 15;
  const int wm = wave >> 1, wn = wave & 1;
  const int bm = blockIdx.x, bn = blockIdx.y;
  floatx4 acc[2][4] = {};
  const int arow = lane >> 2;
  const int ag = lane & 3;

  auto stage = [&](int kt, int buf) {
    unsigned short* sA = smem + buf * 6144;
    unsigned short* sB = sA + 2048;
    int rowA = wave * 16 + arow;
    int gA = ag ^ (rowA & 3);
    gld16(&A[(size_t)(bm * 64 + rowA) * 512 + kt * 32 + gA * 8], &sA[(wave * 16) * 32]);
    for (int p = 0; p < 2; p++) {
      int rowB = p * 64 + wave * 16 + arow;
      int gB = ag ^ (rowB & 3);
      gld16(&Bt[(size_t)(bn * 128 + rowB) * 512 + kt * 32 + gB * 8],
            &sB[(p * 64 + wave * 16) * 32]);
    }
  };

  stage(0, 0);
  for (int kt = 0; kt < 16; kt++) {
    __syncthreads();
    if (kt + 1 < 16) stage(kt + 1, (kt + 1) & 1);
    const unsigned short* sA = smem + (kt & 1) * 6144;
    const unsigned short* sB = sA + 2048;
    bf16x8 aF[2], bF[4];
    int swz = (quad ^ (l16 & 3)) * 8;
    for (int i = 0; i < 2; i++) aF[i] = ld8(&sA[(wm * 32 + i * 16 + l16) * 32 + swz]);
    for (int j = 0; j < 4; j++) bF[j] = ld8(&sB[(wn * 64 + j * 16 + l16) * 32 + swz]);
    for (int i = 0; i < 2; i++)
      for (int j = 0; j < 4; j++)
        acc[i][j] = __builtin_amdgcn_mfma_f32_16x16x32_bf16(aF[i], bF[j], acc[i][j], 0, 0, 0);
  }
  for (int i = 0; i < 2; i++)
    for (int j = 0; j < 4; j++) {
      int gc = bn * 128 + wn * 64 + j * 16 + l16;
      float bb = bo[gc];
      for (int r = 0; r < 4; r++) {
        int gr = bm * 64 + wm * 32 + i * 16 + quad * 4 + r;
        out[(size_t)gr * 512 + gc] = acc[i][j][r] + bb;
      }
    }
}

// ---------------- launch ----------------
extern "C" void kernel_launch(void* const* d_in, const int* in_sizes, int n_in,
                              void* d_out, int out_size, void* d_ws, size_t ws_size,
                              hipStream_t stream) {
  const float* nodes = (const float*)d_in[0];
  const void*  mask  = d_in[1];
  const float* wq    = (const float*)d_in[2];
  const float* bq    = (const float*)d_in[3];
  const float* wkv   = (const float*)d_in[4];
  const float* bkv   = (const float*)d_in[5];
  const float* wo    = (const float*)d_in[6];
  const float* bo    = (const float*)d_in[7];
  float* out = (float*)d_out;

  char* ws = (char*)d_ws;
  unsigned short* XB    = (unsigned short*)(ws + 0);          //  4 MB  bf16 nodes
  unsigned short* WQKVT = (unsigned short*)(ws + 4194304);    //  1.5MB
  unsigned short* WOT   = (unsigned short*)(ws + 5767168);    //  0.5MB
  unsigned short* Qm    = (unsigned short*)(ws + 6291456);    //  4 MB  [16][2048][64]
  unsigned short* Km    = (unsigned short*)(ws + 10485760);   //  4 MB
  unsigned short* VTm   = (unsigned short*)(ws + 18874368);   //  4 MB  [16][64][2048] s-perm
  unsigned short* AOm   = (unsigned short*)(ws + 23068672);   //  4 MB  [4096][512]
  unsigned int*   PM    = (unsigned int*)(ws + 27262976);     //  1 MB  packed mask

  prep_k<<<10624, 256, 0, stream>>>(nodes, mask, wq, wkv, wo, XB, WQKVT, WOT, PM);
  gemm_qkv_k<<<dim3(64, 12), 256, 0, stream>>>(XB, WQKVT, bq, bkv, Qm, Km, VTm);
  attn_k<<<dim3(16, 32), 256, 0, stream>>>(Qm, Km, VTm, PM, AOm);
  gemm_out_k<<<dim3(64, 4), 256, 0, stream>>>(AOm, WOT, bo, out);
}